// Round 2
// baseline (299.038 us; speedup 1.0000x reference)
//
#include <hip/hip_runtime.h>
#include <stdint.h>

#define B_ 8
#define T_ 288
#define N_ 307
#define E_ 4912
#define D_ 64

// ordered-uint encoding for float atomicMax
static __device__ __forceinline__ unsigned f2o(float f) {
    unsigned u = __float_as_uint(f);
    return (u & 0x80000000u) ? ~u : (u | 0x80000000u);
}
static __device__ __forceinline__ float o2f(unsigned k) {
    return __uint_as_float((k & 0x80000000u) ? (k & 0x7fffffffu) : ~k);
}

// ---------- Q[t,d] = pe(t,d) + b_val[d] ----------
__global__ void k_pe(const float* __restrict__ b_val, float* __restrict__ Q) {
    int t = blockIdx.x, d = threadIdx.x;
    int i = d >> 1;
    float div = expf(-(float)(2 * i) * (9.210340371976184f / 64.0f)); // ln(1e4)/64
    float ang = (float)t * div;
    float v = (d & 1) ? cosf(ang) : sinf(ang);
    Q[t * 64 + d] = v + b_val[d];
}

// ---------- h0 = node_features @ W_sta + b_sta + ada_emb ----------
__global__ void k_nf(const float* __restrict__ nfeat, const float* __restrict__ W_sta,
                     const float* __restrict__ b_sta, const float* __restrict__ ada,
                     float* __restrict__ h0) {
    __shared__ float sf[32];
    int n = blockIdx.x, d = threadIdx.x;
    if (d < 32) sf[d] = nfeat[n * 32 + d];
    __syncthreads();
    float a = b_sta[d] + ada[n * 64 + d];
#pragma unroll
    for (int k = 0; k < 32; k++) a += sf[k] * W_sta[k * 64 + d];
    h0[n * 64 + d] = a;
}

// ---------- p = h_in @ W ; ss/st attention coeffs ; init m/den/acc ----------
template <int H, int F>
__global__ void k_proj(const float* __restrict__ hin, const float* __restrict__ W,
                       const float* __restrict__ asrc, const float* __restrict__ atgt,
                       float* __restrict__ p, float* __restrict__ ss, float* __restrict__ st,
                       unsigned* __restrict__ mu, float* __restrict__ den,
                       float* __restrict__ acc) {
    __shared__ float xr[64];
    __shared__ float ps[64];
    int n = blockIdx.x, d = threadIdx.x;
    xr[d] = hin[n * 64 + d];
    acc[n * 64 + d] = 0.0f;
    __syncthreads();
    float pd = 0.0f;
#pragma unroll
    for (int k = 0; k < 64; k++) pd += xr[k] * W[k * 64 + d];
    p[n * 64 + d] = pd;
    ps[d] = pd;
    __syncthreads();
    if (d < H) {
        float s0 = 0.0f, s1 = 0.0f;
#pragma unroll
        for (int f = 0; f < F; f++) {
            s0 += ps[d * F + f] * asrc[d * F + f];
            s1 += ps[d * F + f] * atgt[d * F + f];
        }
        ss[n * H + d] = s0;
        st[n * H + d] = s1;
        mu[n * H + d] = 0u;      // "-inf" placeholder in ordered-uint space (never read for live segments)
        den[n * H + d] = 0.0f;
    }
}

// ---------- edge pass 1: score + segment max ----------
template <int H>
__global__ void k_e1(const int* __restrict__ src, const int* __restrict__ tgt,
                     const float* __restrict__ ss, const float* __restrict__ st,
                     float* __restrict__ esc, unsigned* __restrict__ mu) {
    int tid = blockIdx.x * blockDim.x + threadIdx.x;
    if (tid >= E_ * H) return;
    int e = tid / H, h = tid % H;
    float s = ss[src[e] * H + h] + st[tgt[e] * H + h];
    s = s > 0.0f ? s : 0.2f * s;   // leaky_relu(0.2)
    esc[tid] = s;
    atomicMax(&mu[tgt[e] * H + h], f2o(s));
}

// ---------- edge pass 2: exp + segment denominator ----------
template <int H>
__global__ void k_e2(const int* __restrict__ tgt, const float* __restrict__ esc,
                     const unsigned* __restrict__ mu, float* __restrict__ exb,
                     float* __restrict__ den) {
    int tid = blockIdx.x * blockDim.x + threadIdx.x;
    if (tid >= E_ * H) return;
    int e = tid / H, h = tid % H;
    float m = o2f(mu[tgt[e] * H + h]);
    float ev = expf(esc[tid] - m);
    exb[tid] = ev;
    atomicAdd(&den[tgt[e] * H + h], ev);
}

// ---------- edge pass 3: alpha-weighted scatter-add ----------
template <int H, int F>
__global__ void k_e3(const int* __restrict__ src, const int* __restrict__ tgt,
                     const float* __restrict__ p, const float* __restrict__ exb,
                     const float* __restrict__ den, float* __restrict__ acc) {
    int tid = blockIdx.x * blockDim.x + threadIdx.x;
    if (tid >= E_ * 64) return;
    int e = tid >> 6, d = tid & 63;
    int h = d / F;   // compile-time: F=8 -> d>>3 ; F=64 -> 0
    int tg = tgt[e];
    float a = exb[e * H + h] / (den[tg * H + h] + 1e-16f);
    atomicAdd(&acc[tg * 64 + d], p[src[e] * 64 + d] * a);
}

// ---------- finalize: skip + bias (+ELU) ----------
template <bool IDENT, bool LAST>
__global__ void k_fin(const float* __restrict__ hin, const float* __restrict__ skipW,
                      const float* __restrict__ b, const float* __restrict__ acc,
                      float* __restrict__ hout) {
    __shared__ float xr[64];
    int n = blockIdx.x, d = threadIdx.x;
    xr[d] = hin[n * 64 + d];
    __syncthreads();
    float sk;
    if (IDENT) {
        sk = xr[d];
    } else {
        sk = 0.0f;
#pragma unroll
        for (int k = 0; k < 64; k++) sk += xr[k] * skipW[k * 64 + d];
    }
    float v = acc[n * 64 + d] + sk + b[d];
    if (!LAST) v = v > 0.0f ? v : expm1f(v);   // elu
    hout[n * 64 + d] = v;
}

// ---------- broadcast: out[b,t,n,d] = x*Wv[d] + Q[t,d] + h3[n,d] ----------
__global__ __launch_bounds__(256) void k_big(const float* __restrict__ x,
                                             const float* __restrict__ Q,
                                             const float* __restrict__ Wv,
                                             const float* __restrict__ h3,
                                             float* __restrict__ out) {
    int row = blockIdx.x * 32 + (threadIdx.x >> 3);   // (b,t,n) linear
    int l8 = threadIdx.x & 7;
    int d0 = l8 * 8;
    int n = row % N_;
    int bt = row / N_;
    int t = bt % T_;
    float xv = x[row];
    float4 q0 = *(const float4*)(Q + t * 64 + d0);
    float4 q1 = *(const float4*)(Q + t * 64 + d0 + 4);
    float4 g0 = *(const float4*)(h3 + n * 64 + d0);
    float4 g1 = *(const float4*)(h3 + n * 64 + d0 + 4);
    float4 w0 = *(const float4*)(Wv + d0);
    float4 w1 = *(const float4*)(Wv + d0 + 4);
    float4 o0, o1;
    o0.x = fmaf(xv, w0.x, q0.x + g0.x);
    o0.y = fmaf(xv, w0.y, q0.y + g0.y);
    o0.z = fmaf(xv, w0.z, q0.z + g0.z);
    o0.w = fmaf(xv, w0.w, q0.w + g0.w);
    o1.x = fmaf(xv, w1.x, q1.x + g1.x);
    o1.y = fmaf(xv, w1.y, q1.y + g1.y);
    o1.z = fmaf(xv, w1.z, q1.z + g1.z);
    o1.w = fmaf(xv, w1.w, q1.w + g1.w);
    float* op = out + row * 64 + d0;
    *(float4*)(op) = o0;
    *(float4*)(op + 4) = o1;
}

extern "C" void kernel_launch(void* const* d_in, const int* in_sizes, int n_in,
                              void* d_out, int out_size, void* d_ws, size_t ws_size,
                              hipStream_t stream) {
    const float* x      = (const float*)d_in[0];
    const float* nfeat  = (const float*)d_in[1];
    const int*   eidx   = (const int*)d_in[2];
    // d_in[3] edge_prob unused (load_trans_prob=False)
    const float* W_val  = (const float*)d_in[4];
    const float* b_val  = (const float*)d_in[5];
    const float* W_sta  = (const float*)d_in[6];
    const float* b_sta  = (const float*)d_in[7];
    const float* ada    = (const float*)d_in[8];
    const float* g0W    = (const float*)d_in[9];
    const float* g0as   = (const float*)d_in[10];
    const float* g0at   = (const float*)d_in[11];
    const float* g0b    = (const float*)d_in[12];
    const float* g1W    = (const float*)d_in[13];
    const float* g1as   = (const float*)d_in[14];
    const float* g1at   = (const float*)d_in[15];
    const float* g1b    = (const float*)d_in[16];
    const float* g2W    = (const float*)d_in[17];
    const float* g2as   = (const float*)d_in[18];
    const float* g2at   = (const float*)d_in[19];
    const float* g2b    = (const float*)d_in[20];
    const float* g0skip = (const float*)d_in[21];
    const float* g1skip = (const float*)d_in[22];
    (void)in_sizes; (void)n_in; (void)out_size; (void)ws_size;

    const int* src = eidx;
    const int* tgt = eidx + E_;

    // workspace layout (fp32), ~900 KB total
    float* ws   = (float*)d_ws;
    float* Q    = ws;                 // 288*64
    float* h0   = Q + T_ * 64;        // 307*64
    float* h1   = h0 + N_ * 64;
    float* h2   = h1 + N_ * 64;
    float* h3   = h2 + N_ * 64;
    float* p    = h3 + N_ * 64;
    float* acc  = p + N_ * 64;
    float* ss   = acc + N_ * 64;      // 307*8
    float* st   = ss + N_ * 8;
    unsigned* mu = (unsigned*)(st + N_ * 8);
    float* den  = (float*)mu + N_ * 8;
    float* esc  = den + N_ * 8;       // 4912*8
    float* exb  = esc + E_ * 8;       // 4912*8

    // stage 0: tables
    k_pe<<<T_, 64, 0, stream>>>(b_val, Q);
    k_nf<<<N_, 64, 0, stream>>>(nfeat, W_sta, b_sta, ada, h0);

    const int EB8 = (E_ * 8 + 255) / 256;
    const int EB1 = (E_ * 1 + 255) / 256;
    const int EB64 = (E_ * 64 + 255) / 256;

    // layer 0: H=8, F=8, projected skip, ELU
    k_proj<8, 8><<<N_, 64, 0, stream>>>(h0, g0W, g0as, g0at, p, ss, st, mu, den, acc);
    k_e1<8><<<EB8, 256, 0, stream>>>(src, tgt, ss, st, esc, mu);
    k_e2<8><<<EB8, 256, 0, stream>>>(tgt, esc, mu, exb, den);
    k_e3<8, 8><<<EB64, 256, 0, stream>>>(src, tgt, p, exb, den, acc);
    k_fin<false, false><<<N_, 64, 0, stream>>>(h0, g0skip, g0b, acc, h1);

    // layer 1: H=8, F=8, projected skip, ELU
    k_proj<8, 8><<<N_, 64, 0, stream>>>(h1, g1W, g1as, g1at, p, ss, st, mu, den, acc);
    k_e1<8><<<EB8, 256, 0, stream>>>(src, tgt, ss, st, esc, mu);
    k_e2<8><<<EB8, 256, 0, stream>>>(tgt, esc, mu, exb, den);
    k_e3<8, 8><<<EB64, 256, 0, stream>>>(src, tgt, p, exb, den, acc);
    k_fin<false, false><<<N_, 64, 0, stream>>>(h1, g1skip, g1b, acc, h2);

    // layer 2: H=1, F=64, identity skip, no activation
    k_proj<1, 64><<<N_, 64, 0, stream>>>(h2, g2W, g2as, g2at, p, ss, st, mu, den, acc);
    k_e1<1><<<EB1, 256, 0, stream>>>(src, tgt, ss, st, esc, mu);
    k_e2<1><<<EB1, 256, 0, stream>>>(tgt, esc, mu, exb, den);
    k_e3<1, 64><<<EB64, 256, 0, stream>>>(src, tgt, p, exb, den, acc);
    k_fin<true, true><<<N_, 64, 0, stream>>>(h2, g2W /*unused*/, g2b, acc, h3);

    // broadcast: 707328 rows, 32 rows/block
    const int ROWS = B_ * T_ * N_;                 // 707328
    k_big<<<ROWS / 32, 256, 0, stream>>>(x, Q, W_val, h3, (float*)d_out);
}